// Round 15
// baseline (389.293 us; speedup 1.0000x reference)
//
#include <hip/hip_runtime.h>

#define DI __device__ __forceinline__

typedef unsigned short u16;
typedef unsigned int u32;
typedef __attribute__((ext_vector_type(8))) short shortx8;
typedef __attribute__((ext_vector_type(4))) float floatx4;

DI float u2f(u32 x) { union { u32 u; float f; } v; v.u = x; return v.f; }
DI u32 f2u(float x) { union { u32 u; float f; } v; v.f = x; return v.u; }
DI float bflo(u32 w) { return u2f(w << 16); }
DI float bfhi(u32 w) { return u2f(w & 0xffff0000u); }
DI u16 f2bf(float f) {  // RNE
  u32 u = f2u(f);
  u32 r = (u + 0x7fffu + ((u >> 16) & 1u)) >> 16;
  return (u16)r;
}
DI u32 pack2(float a, float b) { return (u32)f2bf(a) | ((u32)f2bf(b) << 16); }

DI float wsum64(float v) {
  v += __shfl_xor(v, 32);
  v += __shfl_xor(v, 16);
  v += __shfl_xor(v, 8);
  v += __shfl_xor(v, 4);
  v += __shfl_xor(v, 2);
  v += __shfl_xor(v, 1);
  return v;
}

DI float gelu_ex(float y) { return 0.5f * y * (1.0f + erff(y * 0.7071067811865476f)); }
DI float softplus_ex(float x) { return x > 0.f ? x + log1pf(expf(-x)) : log1pf(expf(x)); }

// ---------------- fused precompute: blocks 0..63 transpose w2; blocks 64..65 Lbar/Bbar/C
__global__ __launch_bounds__(256) void k_pre2(
    const float* __restrict__ Lam_re, const float* __restrict__ Lam_im,
    const float* __restrict__ log_step,
    const float* __restrict__ B_re, const float* __restrict__ B_im,
    const float* __restrict__ C_re, const float* __restrict__ C_im,
    const float* __restrict__ w2,
    float* __restrict__ wLbar, float* __restrict__ wBbr, float* __restrict__ wBbi,
    float* __restrict__ wCtr, float* __restrict__ wCti, u16* __restrict__ w2T) {
  if (blockIdx.x < 64) {
    __shared__ float s[128][65];
    int t = threadIdx.x;
    int n0 = blockIdx.x * 64;
    for (int i = 0; i < 32; ++i) {
      int e = i * 256 + t;
      int k = e >> 6, n = e & 63;
      s[k][n] = w2[(size_t)k * 4096 + n0 + n];
    }
    __syncthreads();
    for (int i = 0; i < 16; ++i) {
      int e = i * 256 + t;
      int n = e >> 6, kp = e & 63;
      u32 pk = pack2(s[kp * 2][n], s[kp * 2 + 1][n]);
      ((u32*)w2T)[(size_t)(n0 + n) * 64 + kp] = pk;
    }
  } else {
    int l = blockIdx.x - 64;
    int p = threadIdx.x;
    if (p < 128) {
      int idx = l * 128 + p;
      float step = expf(log_step[idx]);
      float lre = -expf(Lam_re[idx]);
      float lim = Lam_im[idx];
      float er = expf(lre * step);
      float Lr = er * cosf(lim * step);
      float Li = er * sinf(lim * step);
      wLbar[idx * 2] = Lr;
      wLbar[idx * 2 + 1] = Li;
      float inv = 1.0f / (lre * lre + lim * lim);
      float nr = Lr - 1.0f, ni = Li;
      float qr = (nr * lre + ni * lim) * inv;
      float qi = (ni * lre - nr * lim) * inv;
      for (int h = 0; h < 64; ++h) {
        float br = B_re[idx * 64 + h], bim = B_im[idx * 64 + h];
        wBbr[(l * 64 + h) * 128 + p] = qr * br - qi * bim;
        wBbi[(l * 64 + h) * 128 + p] = qr * bim + qi * br;
        wCtr[idx * 64 + h] = C_re[(l * 64 + h) * 128 + p];
        wCti[idx * 64 + h] = C_im[(l * 64 + h) * 128 + p];
      }
    }
  }
}

// ---------------- LN1 + Bu = einsum('ph,blh->blp'); bu packed bf16 (re,im) per u32
__global__ __launch_bounds__(256) void k_ln_bu(
    const float* __restrict__ xin, const float* __restrict__ lnw, const float* __restrict__ lnb,
    const float* __restrict__ wBbr, const float* __restrict__ wBbi,
    float* __restrict__ fxg, u32* __restrict__ bu, int layer) {
  __shared__ float sbr[64 * 128];
  __shared__ float sbi[64 * 128];
  int t = threadIdx.x, w = t >> 6, lane = t & 63;
  {
    const float* br = wBbr + (size_t)layer * 8192;
    const float* bi = wBbi + (size_t)layer * 8192;
    for (int e = t; e < 8192; e += 256) { sbr[e] = br[e]; sbi[e] = bi[e]; }
  }
  float wv = lnw[layer * 64 + lane], bv = lnb[layer * 64 + lane];
  __syncthreads();
  int row0 = blockIdx.x * 32 + w * 8;
  float fxv[8];
#pragma unroll
  for (int rr = 0; rr < 8; ++rr) {
    size_t r = row0 + rr;
    float x = xin[r * 64 + lane];
    float mu = wsum64(x) * 0.015625f;
    float d = x - mu;
    float var = wsum64(d * d) * 0.015625f;
    float fx = d * rsqrtf(var + 1e-5f) * wv + bv;
    fxv[rr] = fx;
    fxg[r * 64 + lane] = fx;
  }
  float ar0[8] = {}, ai0[8] = {}, ar1[8] = {}, ai1[8] = {};
  for (int h = 0; h < 64; ++h) {
    float b0r = sbr[h * 128 + lane], b0i = sbi[h * 128 + lane];
    float b1r = sbr[h * 128 + lane + 64], b1i = sbi[h * 128 + lane + 64];
#pragma unroll
    for (int rr = 0; rr < 8; ++rr) {
      float f = __shfl(fxv[rr], h);
      ar0[rr] = fmaf(b0r, f, ar0[rr]);
      ai0[rr] = fmaf(b0i, f, ai0[rr]);
      ar1[rr] = fmaf(b1r, f, ar1[rr]);
      ai1[rr] = fmaf(b1i, f, ai1[rr]);
    }
  }
#pragma unroll
  for (int rr = 0; rr < 8; ++rr) {
    size_t r = row0 + rr;
    bu[r * 128 + lane] = pack2(ar0[rr], ai0[rr]);
    bu[r * 128 + lane + 64] = pack2(ar1[rr], ai1[rr]);
  }
}

// ---------------- diagonal complex inclusive scan over L, chunked 3-phase (in place, bf16)
__global__ __launch_bounds__(256) void k_scan(u32* __restrict__ bu,
                                              const float* __restrict__ wLbar, int layer) {
  __shared__ float2 carry[16][17];
  int t = threadIdx.x;
  int ck = t >> 4, chain = t & 15;
  int b = blockIdx.x >> 3;
  int p = (blockIdx.x & 7) * 16 + chain;
  float Lr = wLbar[(layer * 128 + p) * 2];
  float Li = wLbar[(layer * 128 + p) * 2 + 1];
  u32* ptr = bu + ((size_t)b * 512 * 128 + p);
  int l0 = ck * 32;
  float xr = 0.f, xi = 0.f;
#pragma unroll 4
  for (int i = 0; i < 32; ++i) {
    u32 v = ptr[(size_t)(l0 + i) * 128];
    float vr = bflo(v), vi = bfhi(v);
    float nr = fmaf(Lr, xr, fmaf(-Li, xi, vr));
    float ni = fmaf(Lr, xi, fmaf(Li, xr, vi));
    xr = nr; xi = ni;
  }
  carry[chain][ck] = make_float2(xr, xi);
  __syncthreads();
  if (t < 16) {
    float ar = Lr, ai = Li;
#pragma unroll
    for (int s = 0; s < 5; ++s) {
      float nr = ar * ar - ai * ai;
      float ni = 2.f * ar * ai;
      ar = nr; ai = ni;
    }
    float cr = 0.f, ci2 = 0.f;
#pragma unroll
    for (int m = 0; m < 16; ++m) {
      float2 loc = carry[t][m];
      carry[t][m] = make_float2(cr, ci2);
      float nr = fmaf(ar, cr, fmaf(-ai, ci2, loc.x));
      float ni = fmaf(ar, ci2, fmaf(ai, cr, loc.y));
      cr = nr; ci2 = ni;
    }
  }
  __syncthreads();
  float2 c0 = carry[chain][ck];
  xr = c0.x; xi = c0.y;
#pragma unroll 4
  for (int i = 0; i < 32; ++i) {
    u32 v = ptr[(size_t)(l0 + i) * 128];
    float vr = bflo(v), vi = bfhi(v);
    float nr = fmaf(Lr, xr, fmaf(-Li, xi, vr));
    float ni = fmaf(Lr, xi, fmaf(Li, xr, vi));
    xr = nr; xi = ni;
    ptr[(size_t)(l0 + i) * 128] = pack2(xr, xi);
  }
}

// ---------------- fused y-projection + GLU FFN (+ toa1 for layer 1); xs packed bf16
__global__ __launch_bounds__(256) void k_yff(
    const u32* __restrict__ xs, const float* __restrict__ wCtr, const float* __restrict__ wCti,
    const float* __restrict__ fxg, const float* __restrict__ Dp,
    const float* __restrict__ ln2w, const float* __restrict__ ln2b,
    const float* __restrict__ encw, const float* __restrict__ decw,
    const float* __restrict__ w1, const float* __restrict__ b1,
    float* __restrict__ xout, u16* __restrict__ h1out, int layer) {
  __shared__ union {
    struct { float ctr[4096]; float cti[4096]; u32 xsh[4][8][64]; } a;
    struct { float enc[8192]; float dec[4096]; } b;
    struct { float w1s[8192]; } c;
  } sm;
  int t = threadIdx.x, w = t >> 6, lane = t & 63;
  int row0 = blockIdx.x * 32 + w * 8;
  float acc[8] = {};
  for (int ph = 0; ph < 2; ++ph) {
    __syncthreads();
    {
      const float* sr = wCtr + ((size_t)layer * 128 + ph * 64) * 64;
      const float* si = wCti + ((size_t)layer * 128 + ph * 64) * 64;
      for (int e = t; e < 4096; e += 256) { sm.a.ctr[e] = sr[e]; sm.a.cti[e] = si[e]; }
    }
#pragma unroll
    for (int rr = 0; rr < 8; ++rr) {
      size_t r = row0 + rr;
      sm.a.xsh[w][rr][lane] = xs[r * 128 + ph * 64 + lane];
    }
    __syncthreads();
    for (int p = 0; p < 64; ++p) {
      float cr = sm.a.ctr[p * 64 + lane];
      float ci = sm.a.cti[p * 64 + lane];
#pragma unroll
      for (int rr = 0; rr < 8; ++rr) {
        u32 xv = sm.a.xsh[w][rr][p];
        acc[rr] = fmaf(cr, bflo(xv), fmaf(-ci, bfhi(xv), acc[rr]));
      }
    }
  }
  float Dv = Dp[layer * 64 + lane];
  float xv[8];
#pragma unroll
  for (int rr = 0; rr < 8; ++rr) {
    size_t r = row0 + rr;
    float u = fxg[r * 64 + lane];
    float y = 2.f * acc[rr] + Dv * u;
    xv[rr] = gelu_ex(y) + u;
  }
  __syncthreads();
  {
    const float* e = encw + (size_t)layer * 8192;
    for (int i = t; i < 8192; i += 256) sm.b.enc[i] = e[i];
    const float* d = decw + (size_t)layer * 4096;
    for (int i = t; i < 4096; i += 256) sm.b.dec[i] = d[i];
  }
  float wv = ln2w[layer * 64 + lane], bv = ln2b[layer * 64 + lane];
  __syncthreads();
  float fx2v[8];
#pragma unroll
  for (int rr = 0; rr < 8; ++rr) {
    float x = xv[rr];
    float mu = wsum64(x) * 0.015625f;
    float d = x - mu;
    float var = wsum64(d * d) * 0.015625f;
    fx2v[rr] = d * rsqrtf(var + 1e-5f) * wv + bv;
  }
  float h0[8] = {}, h1v[8] = {};
  for (int h = 0; h < 64; ++h) {
    float e0 = sm.b.enc[h * 128 + lane], e1 = sm.b.enc[h * 128 + lane + 64];
#pragma unroll
    for (int rr = 0; rr < 8; ++rr) {
      float f = __shfl(fx2v[rr], h);
      h0[rr] = fmaf(e0, f, h0[rr]);
      h1v[rr] = fmaf(e1, f, h1v[rr]);
    }
  }
  float gv[8];
#pragma unroll
  for (int rr = 0; rr < 8; ++rr) gv[rr] = h0[rr] * gelu_ex(h1v[rr]);
  float x2[8];
  {
    float o[8] = {};
    for (int j = 0; j < 64; ++j) {
      float dv = sm.b.dec[j * 64 + lane];
#pragma unroll
      for (int rr = 0; rr < 8; ++rr) {
        float gj = __shfl(gv[rr], j);
        o[rr] = fmaf(dv, gj, o[rr]);
      }
    }
#pragma unroll
    for (int rr = 0; rr < 8; ++rr) x2[rr] = o[rr] + fx2v[rr];
  }
  if (layer == 0) {
#pragma unroll
    for (int rr = 0; rr < 8; ++rr) xout[(size_t)(row0 + rr) * 64 + lane] = x2[rr];
    return;
  }
  __syncthreads();
  for (int i = t; i < 8192; i += 256) sm.c.w1s[i] = w1[i];
  float bb0 = b1[lane], bb1 = b1[lane + 64];
  __syncthreads();
  float a0[8] = {}, a1[8] = {};
  for (int h = 0; h < 64; ++h) {
    float e0 = sm.c.w1s[h * 128 + lane], e1 = sm.c.w1s[h * 128 + lane + 64];
#pragma unroll
    for (int rr = 0; rr < 8; ++rr) {
      float f = __shfl(x2[rr], h);
      a0[rr] = fmaf(e0, f, a0[rr]);
      a1[rr] = fmaf(e1, f, a1[rr]);
    }
  }
#pragma unroll
  for (int rr = 0; rr < 8; ++rr) {
    size_t r = row0 + rr;
    float v0 = softplus_ex(a0[rr] + bb0);
    float v1 = softplus_ex(a1[rr] + bb1);
    int sl = (2 * lane) & 63;
    float ea = __shfl(v0, sl), eb = __shfl(v1, sl);
    float oa = __shfl(v0, sl + 1), ob = __shfl(v1, sl + 1);
    float lo = (lane < 32) ? ea : eb;
    float hi = (lane < 32) ? oa : ob;
    ((u32*)h1out)[r * 64 + lane] = pack2(lo, hi);
  }
}

// ---------------- MFMA big GEMM: X[m][n] = 0.5*dt[m]*(h1@w2 + b2)[m][n]*mask[n] -> bf16
__global__ __launch_bounds__(256) void k_gemm_mfma(
    const u16* __restrict__ w2T, const u16* __restrict__ h1,
    const float* __restrict__ b2, const float* __restrict__ mask,
    const float* __restrict__ dt, u16* __restrict__ Xout) {
  __shared__ __align__(16) u16 As[128 * 128];
  __shared__ __align__(16) u16 Bs[128 * 128];
  int t = threadIdx.x;
  int bn = blockIdx.x;
  int bm = blockIdx.y;
  {
    const u16* srcA = w2T + (size_t)(bn * 128) * 128;
    const u16* srcB = h1 + (size_t)(bm * 128) * 128;
#pragma unroll
    for (int i = 0; i < 8; ++i) {
      int r = i * 16 + (t >> 4);
      int gs = t & 15;
      int gsw = (gs & 8) | ((gs ^ r) & 7);
      uint4 va = *(const uint4*)(srcA + r * 128 + gs * 8);
      *(uint4*)(As + r * 128 + gsw * 8) = va;
      uint4 vb = *(const uint4*)(srcB + r * 128 + gs * 8);
      *(uint4*)(Bs + r * 128 + gsw * 8) = vb;
    }
  }
  __syncthreads();
  int w = t >> 6, l = t & 63;
  int n0 = (w & 1) * 64, m0 = (w >> 1) * 64;
  int lr = l & 15, kg = l >> 4;
  floatx4 acc[4][4];
#pragma unroll
  for (int i = 0; i < 4; ++i)
#pragma unroll
    for (int j = 0; j < 4; ++j) acc[i][j] = (floatx4){0.f, 0.f, 0.f, 0.f};
#pragma unroll
  for (int kk = 0; kk < 4; ++kk) {
    int g = kk * 4 + kg;
    shortx8 af[4], bf[4];
#pragma unroll
    for (int ni = 0; ni < 4; ++ni) {
      int r = n0 + ni * 16 + lr;
      int gsw = (g & 8) | ((g ^ r) & 7);
      af[ni] = *(const shortx8*)(As + r * 128 + gsw * 8);
    }
#pragma unroll
    for (int mi = 0; mi < 4; ++mi) {
      int r = m0 + mi * 16 + lr;
      int gsw = (g & 8) | ((g ^ r) & 7);
      bf[mi] = *(const shortx8*)(Bs + r * 128 + gsw * 8);
    }
#pragma unroll
    for (int ni = 0; ni < 4; ++ni)
#pragma unroll
      for (int mi = 0; mi < 4; ++mi)
        acc[ni][mi] = __builtin_amdgcn_mfma_f32_16x16x32_bf16(af[ni], bf[mi], acc[ni][mi], 0, 0, 0);
  }
  __syncthreads();
  int q = (l >> 4) * 4;
#pragma unroll
  for (int mi = 0; mi < 4; ++mi) {
    int ml = m0 + mi * 16 + lr;
    int m = bm * 128 + ml;
    float dv = 0.5f * dt[m];
#pragma unroll
    for (int ni = 0; ni < 4; ++ni) {
      int nl = n0 + ni * 16 + q;
      int n = bn * 128 + nl;
      float4 bb = *(const float4*)&b2[n];
      float4 mk = *(const float4*)&mask[n];
      floatx4 a = acc[ni][mi];
      float x0 = dv * (a[0] + bb.x) * mk.x;
      float x1 = dv * (a[1] + bb.y) * mk.y;
      float x2 = dv * (a[2] + bb.z) * mk.z;
      float x3 = dv * (a[3] + bb.w) * mk.w;
      u32 lo = pack2(x0, x1);
      u32 hi = pack2(x2, x3);
      int g = nl >> 3;
      int gsw = (g & 8) | ((g ^ ml) & 7);
      *(uint2*)(As + ml * 128 + gsw * 8 + (nl & 7)) = make_uint2(lo, hi);
    }
  }
  __syncthreads();
  int seg = t & 7;
#pragma unroll
  for (int pp = 0; pp < 4; ++pp) {
    int r = pp * 32 + (t >> 3);
#pragma unroll
    for (int ii = 0; ii < 2; ++ii) {
      int g = seg * 2 + ii;
      int gsw = (g & 8) | ((g ^ r) & 7);
      uint4 v = *(const uint4*)(As + r * 128 + gsw * 8);
      *(uint4*)&Xout[(size_t)(bm * 128 + r) * 4096 + bn * 128 + g * 8] = v;
    }
  }
}

// ---------------- fused chunk kernel (2 barriers/j): A_t = I + 2(X+X^2);
// m1 produces E with wave-owned ROWS so m3's af reads stay wave-local (no barrier C).
// S_j = (R_j - I) bf16 row-major written IN PLACE over X_t; compact S15 also emitted.
__global__ __launch_bounds__(256, 4) void k_chunk(u16* __restrict__ Xg,
                                                  u16* __restrict__ S15) {
  __shared__ __align__(16) u16 Xrm[4096];
  __shared__ __align__(16) u16 XTrm[4096];
  __shared__ __align__(16) u16 Erm[4096];
  __shared__ __align__(16) u16 STb[4096];
  __shared__ __align__(16) u16 SOut[4096];
  int t = threadIdx.x, w = t >> 6, l = t & 63;
  int lr = l & 15, kg = l >> 4;
  u16* base = Xg + (size_t)blockIdx.x * 16 * 4096;
  floatx4 sreg[4];
#pragma unroll
  for (int i = 0; i < 4; ++i) sreg[i] = (floatx4){0.f, 0.f, 0.f, 0.f};
  int r0 = (t >> 3) * 2, c0 = (t & 7) * 8, g0 = t & 7;
  int cw = t >> 3;
  uint4 pf0 = *(const uint4*)(base + r0 * 64 + c0);
  uint4 pf1 = *(const uint4*)(base + (r0 + 1) * 64 + c0);
  int q0 = w * 16 + kg * 4;
  int qrow = w * 16 + lr;
  int wr = t >> 2, wg = (t & 3) * 2;
  for (int j = 0; j < 16; ++j) {
    __syncthreads();  // barrier A: prev m1/m3 reads done; SOut packed
    if (j > 0) {
      u16* dst = base + (size_t)(j - 1) * 4096;
      uint4 v0 = *(const uint4*)(SOut + wr * 64 + (((wg + 0) ^ wr) & 7) * 8);
      uint4 v1 = *(const uint4*)(SOut + wr * 64 + (((wg + 1) ^ wr) & 7) * 8);
      *(uint4*)(dst + wr * 64 + wg * 8) = v0;
      *(uint4*)(dst + wr * 64 + wg * 8 + 8) = v1;
    }
    *(uint4*)(Xrm + r0 * 64 + ((g0 ^ r0) & 7) * 8) = pf0;
    *(uint4*)(Xrm + (r0 + 1) * 64 + ((g0 ^ (r0 + 1)) & 7) * 8) = pf1;
    {
      const u16* a = (const u16*)&pf0;
      const u16* bq = (const u16*)&pf1;
#pragma unroll
      for (int i = 0; i < 8; ++i) {
        int ci = (i + t) & 7;
        int cc = c0 + ci;
        u32 val = (u32)a[ci] | ((u32)bq[ci] << 16);
        ((u32*)XTrm)[cc * 32 + (((cw >> 2) ^ cc) & 7) * 4 + (cw & 3)] = val;
      }
    }
#pragma unroll
    for (int j2 = 0; j2 < 4; ++j2) {
      int p = j2 * 16 + lr;
      floatx4 s = sreg[j2];
      float v0 = s[0] + ((p == q0 + 0) ? 1.f : 0.f);
      float v1 = s[1] + ((p == q0 + 1) ? 1.f : 0.f);
      float v2 = s[2] + ((p == q0 + 2) ? 1.f : 0.f);
      float v3 = s[3] + ((p == q0 + 3) ? 1.f : 0.f);
      *(uint2*)(STb + p * 64 + (((q0 >> 3) ^ p) & 7) * 8 + (q0 & 7)) =
          make_uint2(pack2(v0, v1), pack2(v2, v3));
    }
    if (j < 15) {
      const u16* nx = base + (size_t)(j + 1) * 4096;
      pf0 = *(const uint4*)(nx + r0 * 64 + c0);
      pf1 = *(const uint4*)(nx + (r0 + 1) * 64 + c0);
    }
    __syncthreads();  // barrier B: Xrm/XTrm/STb staged
    // m1: X2 = X*X with wave-owned ROWS (bf = wave's Xrm row tile, af loops q-tiles);
    // E = 2(X + X2) -> Erm rows w*16..w*16+15 (wave-local)
    {
      shortx8 bfx0 = *(const shortx8*)(Xrm + qrow * 64 + ((kg ^ qrow) & 7) * 8);
      shortx8 bfx1 = *(const shortx8*)(Xrm + qrow * 64 + (((4 + kg) ^ qrow) & 7) * 8);
      floatx4 acc[4];
#pragma unroll
      for (int i = 0; i < 4; ++i) acc[i] = (floatx4){0.f, 0.f, 0.f, 0.f};
#pragma unroll
      for (int kk = 0; kk < 2; ++kk) {
        int g = kk * 4 + kg;
        shortx8 bf = kk ? bfx1 : bfx0;
#pragma unroll
        for (int j2 = 0; j2 < 4; ++j2) {
          int qr2 = j2 * 16 + lr;
          shortx8 af = *(const shortx8*)(XTrm + qr2 * 64 + ((g ^ qr2) & 7) * 8);
          acc[j2] = __builtin_amdgcn_mfma_f32_16x16x32_bf16(af, bf, acc[j2], 0, 0, 0);
        }
      }
      // lane holds X2[qrow][j2*16 + kg*4 .. +3]
#pragma unroll
      for (int j2 = 0; j2 < 4; ++j2) {
        int qc = j2 * 16 + kg * 4;
        int sw = (((qc >> 3) ^ qrow) & 7) * 8 + (qc & 7);
        uint2 xv = *(const uint2*)(Xrm + qrow * 64 + sw);
        floatx4 a = acc[j2];
        float e0 = 2.f * (bflo(xv.x) + a[0]);
        float e1 = 2.f * (bfhi(xv.x) + a[1]);
        float e2 = 2.f * (bflo(xv.y) + a[2]);
        float e3 = 2.f * (bfhi(xv.y) + a[3]);
        *(uint2*)(Erm + qrow * 64 + sw) = make_uint2(pack2(e0, e1), pack2(e2, e3));
      }
    }
    // m3 (same phase; af reads wave-local Erm rows, DS in-order within wave):
    // S^T += (I+S^T).E^T ; pack SOut (row-major S_j)
    {
      shortx8 ae0 = *(const shortx8*)(Erm + qrow * 64 + ((kg ^ qrow) & 7) * 8);
      shortx8 ae1 = *(const shortx8*)(Erm + qrow * 64 + (((4 + kg) ^ qrow) & 7) * 8);
      floatx4 acc[4];
#pragma unroll
      for (int i = 0; i < 4; ++i) acc[i] = (floatx4){0.f, 0.f, 0.f, 0.f};
#pragma unroll
      for (int kk = 0; kk < 2; ++kk) {
        int g = kk * 4 + kg;
        shortx8 af = kk ? ae1 : ae0;
#pragma unroll
        for (int j2 = 0; j2 < 4; ++j2) {
          int p = j2 * 16 + lr;
          shortx8 bf = *(const shortx8*)(STb + p * 64 + ((g ^ p) & 7) * 8);
          acc[j2] = __builtin_amdgcn_mfma_f32_16x16x32_bf16(af, bf, acc[j2], 0, 0, 0);
        }
      }
#pragma unroll
      for (int j2 = 0; j2 < 4; ++j2) {
        int p = j2 * 16 + lr;
        floatx4 a = acc[j2];
        floatx4 s = sreg[j2];
        s[0] += a[0]; s[1] += a[1]; s[2] += a[2]; s[3] += a[3];
        sreg[j2] = s;
#pragma unroll
        for (int ii = 0; ii < 4; ++ii) {
          int r2 = q0 + ii;
          SOut[r2 * 64 + (((p >> 3) ^ r2) & 7) * 8 + (p & 7)] = f2bf(s[ii]);
        }
      }
    }
  }
  __syncthreads();
  {
    u16* dst = base + (size_t)15 * 4096;
    u16* dst2 = S15 + (size_t)blockIdx.x * 4096;
    uint4 v0 = *(const uint4*)(SOut + wr * 64 + (((wg + 0) ^ wr) & 7) * 8);
    uint4 v1 = *(const uint4*)(SOut + wr * 64 + (((wg + 1) ^ wr) & 7) * 8);
    *(uint4*)(dst + wr * 64 + wg * 8) = v0;
    *(uint4*)(dst + wr * 64 + wg * 8 + 8) = v1;
    *(uint4*)(dst2 + wr * 64 + wg * 8) = v0;
    *(uint4*)(dst2 + wr * 64 + wg * 8 + 8) = v1;
  }
}

// ---------------- carry chain: z_{16(c+1)} = (I + S15_c) z_{16c}; compact S15 reads
__global__ __launch_bounds__(64) void k_carry(const float* __restrict__ zin,
                                              const u16* __restrict__ S15,
                                              float* __restrict__ out) {
  int b = blockIdx.x, l = threadIdx.x;
  uint4 cf[8], nf[8];
  {
    const uint4* M0 = (const uint4*)(S15 + (size_t)(b * 32) * 4096 + l * 64);
#pragma unroll
    for (int g = 0; g < 8; ++g) cf[g] = M0[g];
  }
  float cz = zin[(size_t)b * 512 * 64 + l];
  for (int c = 0; c < 32; ++c) {
    out[((size_t)(b * 512 + c * 16)) * 64 + l] = cz;
    if (c < 31) {
      const uint4* Mn = (const uint4*)(S15 + (size_t)(b * 32 + c + 1) * 4096 + l * 64);
#pragma unroll
      for (int g = 0; g < 8; ++g) nf[g] = Mn[g];
    }
    float a0 = 0.f, a1 = 0.f, a2 = 0.f, a3 = 0.f;
#pragma unroll
    for (int g = 0; g < 8; ++g) {
      uint4 v = cf[g];
      int k = g * 8;
      a0 = fmaf(bflo(v.x), __shfl(cz, k + 0), a0);
      a1 = fmaf(bfhi(v.x), __shfl(cz, k + 1), a1);
      a2 = fmaf(bflo(v.y), __shfl(cz, k + 2), a2);
      a3 = fmaf(bfhi(v.y), __shfl(cz, k + 3), a3);
      a0 = fmaf(bflo(v.z), __shfl(cz, k + 4), a0);
      a1 = fmaf(bfhi(v.z), __shfl(cz, k + 5), a1);
      a2 = fmaf(bflo(v.w), __shfl(cz, k + 6), a2);
      a3 = fmaf(bfhi(v.w), __shfl(cz, k + 7), a3);
    }
    cz += (a0 + a1) + (a2 + a3);
    if (c < 31) {
#pragma unroll
      for (int g = 0; g < 8; ++g) cf[g] = nf[g];
    }
  }
}

// ---------------- apply: z_{16c+j+1} = (I + S_j) z_{16c}; row-major S, vectorized rows
__global__ __launch_bounds__(256) void k_apply(const u16* __restrict__ R,
                                               float* __restrict__ out) {
  __shared__ float carr[64];
  int t = threadIdx.x, w = t >> 6, l = t & 63;
  int b = blockIdx.x >> 5, c = blockIdx.x & 31;
  const u16* Rb = R + ((size_t)(b * 512 + c * 16)) * 4096;
  if (t < 64) carr[t] = out[((size_t)(b * 512 + c * 16)) * 64 + t];
  __syncthreads();
  float zl = carr[l];
  for (int j = w; j < 15; j += 4) {
    const uint4* M = (const uint4*)(Rb + (size_t)j * 4096 + l * 64);
    float a0 = 0.f, a1 = 0.f, a2 = 0.f, a3 = 0.f;
#pragma unroll
    for (int g = 0; g < 8; ++g) {
      uint4 v = M[g];
      const float* zb = &carr[g * 8];
      a0 = fmaf(bflo(v.x), zb[0], a0);
      a1 = fmaf(bfhi(v.x), zb[1], a1);
      a2 = fmaf(bflo(v.y), zb[2], a2);
      a3 = fmaf(bfhi(v.y), zb[3], a3);
      a0 = fmaf(bflo(v.z), zb[4], a0);
      a1 = fmaf(bfhi(v.z), zb[5], a1);
      a2 = fmaf(bflo(v.w), zb[6], a2);
      a3 = fmaf(bfhi(v.w), zb[7], a3);
    }
    out[((size_t)(b * 512 + c * 16 + j + 1)) * 64 + l] = zl + ((a0 + a1) + (a2 + a3));
  }
}

extern "C" void kernel_launch(void* const* d_in, const int* in_sizes, int n_in,
                              void* d_out, int out_size, void* d_ws, size_t ws_size,
                              hipStream_t stream) {
  const float* z_input  = (const float*)d_in[0];
  const float* dt       = (const float*)d_in[1];
  const float* ln1_w    = (const float*)d_in[2];
  const float* ln1_b    = (const float*)d_in[3];
  const float* Lam_re   = (const float*)d_in[4];
  const float* Lam_im   = (const float*)d_in[5];
  const float* B_re     = (const float*)d_in[6];
  const float* B_im     = (const float*)d_in[7];
  const float* C_re     = (const float*)d_in[8];
  const float* C_im     = (const float*)d_in[9];
  const float* Dp       = (const float*)d_in[10];
  const float* log_step = (const float*)d_in[11];
  const float* ln2_w    = (const float*)d_in[12];
  const float* ln2_b    = (const float*)d_in[13];
  const float* ff_enc   = (const float*)d_in[14];
  const float* ff_dec   = (const float*)d_in[15];
  const float* toA_w1   = (const float*)d_in[16];
  const float* toA_b1   = (const float*)d_in[17];
  const float* toA_w2   = (const float*)d_in[18];
  const float* toA_b2   = (const float*)d_in[19];
  const float* mask_A   = (const float*)d_in[20];

  char* ws = (char*)d_ws;
  float* wLbar = (float*)(ws + 0);
  float* wBbr  = (float*)(ws + 2048);
  float* wBbi  = (float*)(ws + 67584);
  float* wCtr  = (float*)(ws + 133120);
  float* wCti  = (float*)(ws + 198656);
  float* wfx   = (float*)(ws + 264192);
  float* wx    = (float*)(ws + 4458496);
  u32* wbu     = (u32*)(ws + 8652800);      // [16384][128] packed bf16 (re,im)
  u16* wS15    = (u16*)(ws + 17041408);     // [1024][4096] bf16 compact
  u16* wh1     = (u16*)(ws + 25430016);     // [16384][128] bf16
  u16* w2T     = (u16*)(ws + 29624320);     // [4096][128] bf16
  u16* wX      = (u16*)(ws + 30672896);     // [16384][4096] bf16 (X, then S in place)
  if (ws_size < 164890624ull) return;

  k_pre2<<<66, 256, 0, stream>>>(Lam_re, Lam_im, log_step, B_re, B_im, C_re, C_im,
                                 toA_w2, wLbar, wBbr, wBbi, wCtr, wCti, w2T);
  for (int l = 0; l < 2; ++l) {
    const float* xin = (l == 0) ? z_input : wx;
    k_ln_bu<<<512, 256, 0, stream>>>(xin, ln1_w, ln1_b, wBbr, wBbi, wfx, wbu, l);
    k_scan<<<256, 256, 0, stream>>>(wbu, wLbar, l);
    k_yff<<<512, 256, 0, stream>>>(wbu, wCtr, wCti, wfx, Dp, ln2_w, ln2_b, ff_enc, ff_dec,
                                   toA_w1, toA_b1, wx, wh1, l);
  }
  k_gemm_mfma<<<dim3(32, 128), 256, 0, stream>>>(w2T, wh1, toA_b2, mask_A, dt, wX);
  k_chunk<<<1024, 256, 0, stream>>>(wX, wS15);
  k_carry<<<32, 64, 0, stream>>>(z_input, wS15, (float*)d_out);
  k_apply<<<1024, 256, 0, stream>>>(wX, (float*)d_out);
}

// Round 16
// 385.766 us; speedup vs baseline: 1.0091x; 1.0091x over previous
//
#include <hip/hip_runtime.h>

#define DI __device__ __forceinline__

typedef unsigned short u16;
typedef unsigned int u32;
typedef __attribute__((ext_vector_type(8))) short shortx8;
typedef __attribute__((ext_vector_type(4))) float floatx4;

DI float u2f(u32 x) { union { u32 u; float f; } v; v.u = x; return v.f; }
DI u32 f2u(float x) { union { u32 u; float f; } v; v.f = x; return v.u; }
DI float bflo(u32 w) { return u2f(w << 16); }
DI float bfhi(u32 w) { return u2f(w & 0xffff0000u); }
DI u16 f2bf(float f) {  // RNE
  u32 u = f2u(f);
  u32 r = (u + 0x7fffu + ((u >> 16) & 1u)) >> 16;
  return (u16)r;
}
DI u32 pack2(float a, float b) { return (u32)f2bf(a) | ((u32)f2bf(b) << 16); }

DI float wsum64(float v) {
  v += __shfl_xor(v, 32);
  v += __shfl_xor(v, 16);
  v += __shfl_xor(v, 8);
  v += __shfl_xor(v, 4);
  v += __shfl_xor(v, 2);
  v += __shfl_xor(v, 1);
  return v;
}

DI float gelu_ex(float y) { return 0.5f * y * (1.0f + erff(y * 0.7071067811865476f)); }
DI float softplus_ex(float x) { return x > 0.f ? x + log1pf(expf(-x)) : log1pf(expf(x)); }

// ---------------- fused precompute: blocks 0..63 transpose w2; blocks 64..65 Lbar/Bbar/C
__global__ __launch_bounds__(256) void k_pre2(
    const float* __restrict__ Lam_re, const float* __restrict__ Lam_im,
    const float* __restrict__ log_step,
    const float* __restrict__ B_re, const float* __restrict__ B_im,
    const float* __restrict__ C_re, const float* __restrict__ C_im,
    const float* __restrict__ w2,
    float* __restrict__ wLbar, float* __restrict__ wBbr, float* __restrict__ wBbi,
    float* __restrict__ wCtr, float* __restrict__ wCti, u16* __restrict__ w2T) {
  if (blockIdx.x < 64) {
    __shared__ float s[128][65];
    int t = threadIdx.x;
    int n0 = blockIdx.x * 64;
    for (int i = 0; i < 32; ++i) {
      int e = i * 256 + t;
      int k = e >> 6, n = e & 63;
      s[k][n] = w2[(size_t)k * 4096 + n0 + n];
    }
    __syncthreads();
    for (int i = 0; i < 16; ++i) {
      int e = i * 256 + t;
      int n = e >> 6, kp = e & 63;
      u32 pk = pack2(s[kp * 2][n], s[kp * 2 + 1][n]);
      ((u32*)w2T)[(size_t)(n0 + n) * 64 + kp] = pk;
    }
  } else {
    int l = blockIdx.x - 64;
    int p = threadIdx.x;
    if (p < 128) {
      int idx = l * 128 + p;
      float step = expf(log_step[idx]);
      float lre = -expf(Lam_re[idx]);
      float lim = Lam_im[idx];
      float er = expf(lre * step);
      float Lr = er * cosf(lim * step);
      float Li = er * sinf(lim * step);
      wLbar[idx * 2] = Lr;
      wLbar[idx * 2 + 1] = Li;
      float inv = 1.0f / (lre * lre + lim * lim);
      float nr = Lr - 1.0f, ni = Li;
      float qr = (nr * lre + ni * lim) * inv;
      float qi = (ni * lre - nr * lim) * inv;
      for (int h = 0; h < 64; ++h) {
        float br = B_re[idx * 64 + h], bim = B_im[idx * 64 + h];
        wBbr[(l * 64 + h) * 128 + p] = qr * br - qi * bim;
        wBbi[(l * 64 + h) * 128 + p] = qr * bim + qi * br;
        wCtr[idx * 64 + h] = C_re[(l * 64 + h) * 128 + p];
        wCti[idx * 64 + h] = C_im[(l * 64 + h) * 128 + p];
      }
    }
  }
}

// ---------------- LN1 + Bu = einsum('ph,blh->blp'); bu packed bf16 (re,im) per u32
__global__ __launch_bounds__(256) void k_ln_bu(
    const float* __restrict__ xin, const float* __restrict__ lnw, const float* __restrict__ lnb,
    const float* __restrict__ wBbr, const float* __restrict__ wBbi,
    float* __restrict__ fxg, u32* __restrict__ bu, int layer) {
  __shared__ float sbr[64 * 128];
  __shared__ float sbi[64 * 128];
  int t = threadIdx.x, w = t >> 6, lane = t & 63;
  {
    const float* br = wBbr + (size_t)layer * 8192;
    const float* bi = wBbi + (size_t)layer * 8192;
    for (int e = t; e < 8192; e += 256) { sbr[e] = br[e]; sbi[e] = bi[e]; }
  }
  float wv = lnw[layer * 64 + lane], bv = lnb[layer * 64 + lane];
  __syncthreads();
  int row0 = blockIdx.x * 32 + w * 8;
  float fxv[8];
#pragma unroll
  for (int rr = 0; rr < 8; ++rr) {
    size_t r = row0 + rr;
    float x = xin[r * 64 + lane];
    float mu = wsum64(x) * 0.015625f;
    float d = x - mu;
    float var = wsum64(d * d) * 0.015625f;
    float fx = d * rsqrtf(var + 1e-5f) * wv + bv;
    fxv[rr] = fx;
    fxg[r * 64 + lane] = fx;
  }
  float ar0[8] = {}, ai0[8] = {}, ar1[8] = {}, ai1[8] = {};
  for (int h = 0; h < 64; ++h) {
    float b0r = sbr[h * 128 + lane], b0i = sbi[h * 128 + lane];
    float b1r = sbr[h * 128 + lane + 64], b1i = sbi[h * 128 + lane + 64];
#pragma unroll
    for (int rr = 0; rr < 8; ++rr) {
      float f = __shfl(fxv[rr], h);
      ar0[rr] = fmaf(b0r, f, ar0[rr]);
      ai0[rr] = fmaf(b0i, f, ai0[rr]);
      ar1[rr] = fmaf(b1r, f, ar1[rr]);
      ai1[rr] = fmaf(b1i, f, ai1[rr]);
    }
  }
#pragma unroll
  for (int rr = 0; rr < 8; ++rr) {
    size_t r = row0 + rr;
    bu[r * 128 + lane] = pack2(ar0[rr], ai0[rr]);
    bu[r * 128 + lane + 64] = pack2(ar1[rr], ai1[rr]);
  }
}

// ---------------- diagonal complex inclusive scan over L, chunked 3-phase (in place, bf16)
__global__ __launch_bounds__(256) void k_scan(u32* __restrict__ bu,
                                              const float* __restrict__ wLbar, int layer) {
  __shared__ float2 carry[16][17];
  int t = threadIdx.x;
  int ck = t >> 4, chain = t & 15;
  int b = blockIdx.x >> 3;
  int p = (blockIdx.x & 7) * 16 + chain;
  float Lr = wLbar[(layer * 128 + p) * 2];
  float Li = wLbar[(layer * 128 + p) * 2 + 1];
  u32* ptr = bu + ((size_t)b * 512 * 128 + p);
  int l0 = ck * 32;
  float xr = 0.f, xi = 0.f;
#pragma unroll 4
  for (int i = 0; i < 32; ++i) {
    u32 v = ptr[(size_t)(l0 + i) * 128];
    float vr = bflo(v), vi = bfhi(v);
    float nr = fmaf(Lr, xr, fmaf(-Li, xi, vr));
    float ni = fmaf(Lr, xi, fmaf(Li, xr, vi));
    xr = nr; xi = ni;
  }
  carry[chain][ck] = make_float2(xr, xi);
  __syncthreads();
  if (t < 16) {
    float ar = Lr, ai = Li;
#pragma unroll
    for (int s = 0; s < 5; ++s) {
      float nr = ar * ar - ai * ai;
      float ni = 2.f * ar * ai;
      ar = nr; ai = ni;
    }
    float cr = 0.f, ci2 = 0.f;
#pragma unroll
    for (int m = 0; m < 16; ++m) {
      float2 loc = carry[t][m];
      carry[t][m] = make_float2(cr, ci2);
      float nr = fmaf(ar, cr, fmaf(-ai, ci2, loc.x));
      float ni = fmaf(ar, ci2, fmaf(ai, cr, loc.y));
      cr = nr; ci2 = ni;
    }
  }
  __syncthreads();
  float2 c0 = carry[chain][ck];
  xr = c0.x; xi = c0.y;
#pragma unroll 4
  for (int i = 0; i < 32; ++i) {
    u32 v = ptr[(size_t)(l0 + i) * 128];
    float vr = bflo(v), vi = bfhi(v);
    float nr = fmaf(Lr, xr, fmaf(-Li, xi, vr));
    float ni = fmaf(Lr, xi, fmaf(Li, xr, vi));
    xr = nr; xi = ni;
    ptr[(size_t)(l0 + i) * 128] = pack2(xr, xi);
  }
}

// ---------------- fused y-projection + GLU FFN (+ toa1 for layer 1); xs packed bf16
__global__ __launch_bounds__(256) void k_yff(
    const u32* __restrict__ xs, const float* __restrict__ wCtr, const float* __restrict__ wCti,
    const float* __restrict__ fxg, const float* __restrict__ Dp,
    const float* __restrict__ ln2w, const float* __restrict__ ln2b,
    const float* __restrict__ encw, const float* __restrict__ decw,
    const float* __restrict__ w1, const float* __restrict__ b1,
    float* __restrict__ xout, u16* __restrict__ h1out, int layer) {
  __shared__ union {
    struct { float ctr[4096]; float cti[4096]; u32 xsh[4][8][64]; } a;
    struct { float enc[8192]; float dec[4096]; } b;
    struct { float w1s[8192]; } c;
  } sm;
  int t = threadIdx.x, w = t >> 6, lane = t & 63;
  int row0 = blockIdx.x * 32 + w * 8;
  float acc[8] = {};
  for (int ph = 0; ph < 2; ++ph) {
    __syncthreads();
    {
      const float* sr = wCtr + ((size_t)layer * 128 + ph * 64) * 64;
      const float* si = wCti + ((size_t)layer * 128 + ph * 64) * 64;
      for (int e = t; e < 4096; e += 256) { sm.a.ctr[e] = sr[e]; sm.a.cti[e] = si[e]; }
    }
#pragma unroll
    for (int rr = 0; rr < 8; ++rr) {
      size_t r = row0 + rr;
      sm.a.xsh[w][rr][lane] = xs[r * 128 + ph * 64 + lane];
    }
    __syncthreads();
    for (int p = 0; p < 64; ++p) {
      float cr = sm.a.ctr[p * 64 + lane];
      float ci = sm.a.cti[p * 64 + lane];
#pragma unroll
      for (int rr = 0; rr < 8; ++rr) {
        u32 xv = sm.a.xsh[w][rr][p];
        acc[rr] = fmaf(cr, bflo(xv), fmaf(-ci, bfhi(xv), acc[rr]));
      }
    }
  }
  float Dv = Dp[layer * 64 + lane];
  float xv[8];
#pragma unroll
  for (int rr = 0; rr < 8; ++rr) {
    size_t r = row0 + rr;
    float u = fxg[r * 64 + lane];
    float y = 2.f * acc[rr] + Dv * u;
    xv[rr] = gelu_ex(y) + u;
  }
  __syncthreads();
  {
    const float* e = encw + (size_t)layer * 8192;
    for (int i = t; i < 8192; i += 256) sm.b.enc[i] = e[i];
    const float* d = decw + (size_t)layer * 4096;
    for (int i = t; i < 4096; i += 256) sm.b.dec[i] = d[i];
  }
  float wv = ln2w[layer * 64 + lane], bv = ln2b[layer * 64 + lane];
  __syncthreads();
  float fx2v[8];
#pragma unroll
  for (int rr = 0; rr < 8; ++rr) {
    float x = xv[rr];
    float mu = wsum64(x) * 0.015625f;
    float d = x - mu;
    float var = wsum64(d * d) * 0.015625f;
    fx2v[rr] = d * rsqrtf(var + 1e-5f) * wv + bv;
  }
  float h0[8] = {}, h1v[8] = {};
  for (int h = 0; h < 64; ++h) {
    float e0 = sm.b.enc[h * 128 + lane], e1 = sm.b.enc[h * 128 + lane + 64];
#pragma unroll
    for (int rr = 0; rr < 8; ++rr) {
      float f = __shfl(fx2v[rr], h);
      h0[rr] = fmaf(e0, f, h0[rr]);
      h1v[rr] = fmaf(e1, f, h1v[rr]);
    }
  }
  float gv[8];
#pragma unroll
  for (int rr = 0; rr < 8; ++rr) gv[rr] = h0[rr] * gelu_ex(h1v[rr]);
  float x2[8];
  {
    float o[8] = {};
    for (int j = 0; j < 64; ++j) {
      float dv = sm.b.dec[j * 64 + lane];
#pragma unroll
      for (int rr = 0; rr < 8; ++rr) {
        float gj = __shfl(gv[rr], j);
        o[rr] = fmaf(dv, gj, o[rr]);
      }
    }
#pragma unroll
    for (int rr = 0; rr < 8; ++rr) x2[rr] = o[rr] + fx2v[rr];
  }
  if (layer == 0) {
#pragma unroll
    for (int rr = 0; rr < 8; ++rr) xout[(size_t)(row0 + rr) * 64 + lane] = x2[rr];
    return;
  }
  __syncthreads();
  for (int i = t; i < 8192; i += 256) sm.c.w1s[i] = w1[i];
  float bb0 = b1[lane], bb1 = b1[lane + 64];
  __syncthreads();
  float a0[8] = {}, a1[8] = {};
  for (int h = 0; h < 64; ++h) {
    float e0 = sm.c.w1s[h * 128 + lane], e1 = sm.c.w1s[h * 128 + lane + 64];
#pragma unroll
    for (int rr = 0; rr < 8; ++rr) {
      float f = __shfl(x2[rr], h);
      a0[rr] = fmaf(e0, f, a0[rr]);
      a1[rr] = fmaf(e1, f, a1[rr]);
    }
  }
#pragma unroll
  for (int rr = 0; rr < 8; ++rr) {
    size_t r = row0 + rr;
    float v0 = softplus_ex(a0[rr] + bb0);
    float v1 = softplus_ex(a1[rr] + bb1);
    int sl = (2 * lane) & 63;
    float ea = __shfl(v0, sl), eb = __shfl(v1, sl);
    float oa = __shfl(v0, sl + 1), ob = __shfl(v1, sl + 1);
    float lo = (lane < 32) ? ea : eb;
    float hi = (lane < 32) ? oa : ob;
    ((u32*)h1out)[r * 64 + lane] = pack2(lo, hi);
  }
}

// ---------------- MFMA big GEMM: X[m][n] = 0.5*dt[m]*(h1@w2 + b2)[m][n]*mask[n] -> bf16
__global__ __launch_bounds__(256) void k_gemm_mfma(
    const u16* __restrict__ w2T, const u16* __restrict__ h1,
    const float* __restrict__ b2, const float* __restrict__ mask,
    const float* __restrict__ dt, u16* __restrict__ Xout) {
  __shared__ __align__(16) u16 As[128 * 128];
  __shared__ __align__(16) u16 Bs[128 * 128];
  int t = threadIdx.x;
  int bn = blockIdx.x;
  int bm = blockIdx.y;
  {
    const u16* srcA = w2T + (size_t)(bn * 128) * 128;
    const u16* srcB = h1 + (size_t)(bm * 128) * 128;
#pragma unroll
    for (int i = 0; i < 8; ++i) {
      int r = i * 16 + (t >> 4);
      int gs = t & 15;
      int gsw = (gs & 8) | ((gs ^ r) & 7);
      uint4 va = *(const uint4*)(srcA + r * 128 + gs * 8);
      *(uint4*)(As + r * 128 + gsw * 8) = va;
      uint4 vb = *(const uint4*)(srcB + r * 128 + gs * 8);
      *(uint4*)(Bs + r * 128 + gsw * 8) = vb;
    }
  }
  __syncthreads();
  int w = t >> 6, l = t & 63;
  int n0 = (w & 1) * 64, m0 = (w >> 1) * 64;
  int lr = l & 15, kg = l >> 4;
  floatx4 acc[4][4];
#pragma unroll
  for (int i = 0; i < 4; ++i)
#pragma unroll
    for (int j = 0; j < 4; ++j) acc[i][j] = (floatx4){0.f, 0.f, 0.f, 0.f};
#pragma unroll
  for (int kk = 0; kk < 4; ++kk) {
    int g = kk * 4 + kg;
    shortx8 af[4], bf[4];
#pragma unroll
    for (int ni = 0; ni < 4; ++ni) {
      int r = n0 + ni * 16 + lr;
      int gsw = (g & 8) | ((g ^ r) & 7);
      af[ni] = *(const shortx8*)(As + r * 128 + gsw * 8);
    }
#pragma unroll
    for (int mi = 0; mi < 4; ++mi) {
      int r = m0 + mi * 16 + lr;
      int gsw = (g & 8) | ((g ^ r) & 7);
      bf[mi] = *(const shortx8*)(Bs + r * 128 + gsw * 8);
    }
#pragma unroll
    for (int ni = 0; ni < 4; ++ni)
#pragma unroll
      for (int mi = 0; mi < 4; ++mi)
        acc[ni][mi] = __builtin_amdgcn_mfma_f32_16x16x32_bf16(af[ni], bf[mi], acc[ni][mi], 0, 0, 0);
  }
  __syncthreads();
  int q = (l >> 4) * 4;
#pragma unroll
  for (int mi = 0; mi < 4; ++mi) {
    int ml = m0 + mi * 16 + lr;
    int m = bm * 128 + ml;
    float dv = 0.5f * dt[m];
#pragma unroll
    for (int ni = 0; ni < 4; ++ni) {
      int nl = n0 + ni * 16 + q;
      int n = bn * 128 + nl;
      float4 bb = *(const float4*)&b2[n];
      float4 mk = *(const float4*)&mask[n];
      floatx4 a = acc[ni][mi];
      float x0 = dv * (a[0] + bb.x) * mk.x;
      float x1 = dv * (a[1] + bb.y) * mk.y;
      float x2 = dv * (a[2] + bb.z) * mk.z;
      float x3 = dv * (a[3] + bb.w) * mk.w;
      u32 lo = pack2(x0, x1);
      u32 hi = pack2(x2, x3);
      int g = nl >> 3;
      int gsw = (g & 8) | ((g ^ ml) & 7);
      *(uint2*)(As + ml * 128 + gsw * 8 + (nl & 7)) = make_uint2(lo, hi);
    }
  }
  __syncthreads();
  int seg = t & 7;
#pragma unroll
  for (int pp = 0; pp < 4; ++pp) {
    int r = pp * 32 + (t >> 3);
#pragma unroll
    for (int ii = 0; ii < 2; ++ii) {
      int g = seg * 2 + ii;
      int gsw = (g & 8) | ((g ^ r) & 7);
      uint4 v = *(const uint4*)(As + r * 128 + gsw * 8);
      *(uint4*)&Xout[(size_t)(bm * 128 + r) * 4096 + bn * 128 + g * 8] = v;
    }
  }
}

// ---------------- fused chunk kernel (round-7 structure): A_t = I + 2(X+X^2);
// S_j = (R_j - I) bf16 row-major written IN PLACE over X_t; compact S15 also emitted.
__global__ __launch_bounds__(256, 4) void k_chunk(u16* __restrict__ Xg,
                                                  u16* __restrict__ S15) {
  __shared__ __align__(16) u16 Xrm[4096];
  __shared__ __align__(16) u16 XTrm[4096];
  __shared__ __align__(16) u16 Erm[4096];
  __shared__ __align__(16) u16 STb[4096];
  __shared__ __align__(16) u16 SOut[4096];
  int t = threadIdx.x, w = t >> 6, l = t & 63;
  int lr = l & 15, kg = l >> 4;
  u16* base = Xg + (size_t)blockIdx.x * 16 * 4096;
  floatx4 sreg[4];
#pragma unroll
  for (int i = 0; i < 4; ++i) sreg[i] = (floatx4){0.f, 0.f, 0.f, 0.f};
  int r0 = (t >> 3) * 2, c0 = (t & 7) * 8, g0 = t & 7;
  int cw = t >> 3;
  uint4 pf0 = *(const uint4*)(base + r0 * 64 + c0);
  uint4 pf1 = *(const uint4*)(base + (r0 + 1) * 64 + c0);
  int q0 = w * 16 + kg * 4;
  int qrow = w * 16 + lr;
  int wr = t >> 2, wg = (t & 3) * 2;
  for (int j = 0; j < 16; ++j) {
    __syncthreads();
    if (j > 0) {
      u16* dst = base + (size_t)(j - 1) * 4096;
      uint4 v0 = *(const uint4*)(SOut + wr * 64 + (((wg + 0) ^ wr) & 7) * 8);
      uint4 v1 = *(const uint4*)(SOut + wr * 64 + (((wg + 1) ^ wr) & 7) * 8);
      *(uint4*)(dst + wr * 64 + wg * 8) = v0;
      *(uint4*)(dst + wr * 64 + wg * 8 + 8) = v1;
    }
    *(uint4*)(Xrm + r0 * 64 + ((g0 ^ r0) & 7) * 8) = pf0;
    *(uint4*)(Xrm + (r0 + 1) * 64 + ((g0 ^ (r0 + 1)) & 7) * 8) = pf1;
    {
      const u16* a = (const u16*)&pf0;
      const u16* bq = (const u16*)&pf1;
#pragma unroll
      for (int i = 0; i < 8; ++i) {
        int ci = (i + t) & 7;
        int cc = c0 + ci;
        u32 val = (u32)a[ci] | ((u32)bq[ci] << 16);
        ((u32*)XTrm)[cc * 32 + (((cw >> 2) ^ cc) & 7) * 4 + (cw & 3)] = val;
      }
    }
#pragma unroll
    for (int j2 = 0; j2 < 4; ++j2) {
      int p = j2 * 16 + lr;
      floatx4 s = sreg[j2];
      float v0 = s[0] + ((p == q0 + 0) ? 1.f : 0.f);
      float v1 = s[1] + ((p == q0 + 1) ? 1.f : 0.f);
      float v2 = s[2] + ((p == q0 + 2) ? 1.f : 0.f);
      float v3 = s[3] + ((p == q0 + 3) ? 1.f : 0.f);
      *(uint2*)(STb + p * 64 + (((q0 >> 3) ^ p) & 7) * 8 + (q0 & 7)) =
          make_uint2(pack2(v0, v1), pack2(v2, v3));
    }
    if (j < 15) {
      const u16* nx = base + (size_t)(j + 1) * 4096;
      pf0 = *(const uint4*)(nx + r0 * 64 + c0);
      pf1 = *(const uint4*)(nx + (r0 + 1) * 64 + c0);
    }
    __syncthreads();
    shortx8 afx0 = *(const shortx8*)(XTrm + qrow * 64 + ((kg ^ qrow) & 7) * 8);
    shortx8 afx1 = *(const shortx8*)(XTrm + qrow * 64 + (((4 + kg) ^ qrow) & 7) * 8);
    {
      floatx4 acc[4];
#pragma unroll
      for (int i = 0; i < 4; ++i) acc[i] = (floatx4){0.f, 0.f, 0.f, 0.f};
#pragma unroll
      for (int kk = 0; kk < 2; ++kk) {
        int g = kk * 4 + kg;
        shortx8 af = kk ? afx1 : afx0;
#pragma unroll
        for (int j2 = 0; j2 < 4; ++j2) {
          int p = j2 * 16 + lr;
          shortx8 bf = *(const shortx8*)(Xrm + p * 64 + ((g ^ p) & 7) * 8);
          acc[j2] = __builtin_amdgcn_mfma_f32_16x16x32_bf16(af, bf, acc[j2], 0, 0, 0);
        }
      }
#pragma unroll
      for (int j2 = 0; j2 < 4; ++j2) {
        int p = j2 * 16 + lr;
        int sw = (((q0 >> 3) ^ p) & 7) * 8 + (q0 & 7);
        uint2 xv = *(const uint2*)(Xrm + p * 64 + sw);
        floatx4 a = acc[j2];
        float e0 = 2.f * (bflo(xv.x) + a[0]);
        float e1 = 2.f * (bfhi(xv.x) + a[1]);
        float e2 = 2.f * (bflo(xv.y) + a[2]);
        float e3 = 2.f * (bfhi(xv.y) + a[3]);
        *(uint2*)(Erm + p * 64 + sw) = make_uint2(pack2(e0, e1), pack2(e2, e3));
      }
    }
    __syncthreads();
    {
      floatx4 acc[4];
#pragma unroll
      for (int i = 0; i < 4; ++i) acc[i] = (floatx4){0.f, 0.f, 0.f, 0.f};
#pragma unroll
      for (int kk = 0; kk < 2; ++kk) {
        int g = kk * 4 + kg;
        shortx8 af = *(const shortx8*)(Erm + qrow * 64 + ((g ^ qrow) & 7) * 8);
#pragma unroll
        for (int j2 = 0; j2 < 4; ++j2) {
          int p = j2 * 16 + lr;
          shortx8 bf = *(const shortx8*)(STb + p * 64 + ((g ^ p) & 7) * 8);
          acc[j2] = __builtin_amdgcn_mfma_f32_16x16x32_bf16(af, bf, acc[j2], 0, 0, 0);
        }
      }
#pragma unroll
      for (int j2 = 0; j2 < 4; ++j2) {
        int p = j2 * 16 + lr;
        floatx4 a = acc[j2];
        floatx4 s = sreg[j2];
        s[0] += a[0]; s[1] += a[1]; s[2] += a[2]; s[3] += a[3];
        sreg[j2] = s;
#pragma unroll
        for (int ii = 0; ii < 4; ++ii) {
          int r2 = q0 + ii;
          SOut[r2 * 64 + (((p >> 3) ^ r2) & 7) * 8 + (p & 7)] = f2bf(s[ii]);
        }
      }
    }
  }
  __syncthreads();
  {
    u16* dst = base + (size_t)15 * 4096;
    u16* dst2 = S15 + (size_t)blockIdx.x * 4096;
    uint4 v0 = *(const uint4*)(SOut + wr * 64 + (((wg + 0) ^ wr) & 7) * 8);
    uint4 v1 = *(const uint4*)(SOut + wr * 64 + (((wg + 1) ^ wr) & 7) * 8);
    *(uint4*)(dst + wr * 64 + wg * 8) = v0;
    *(uint4*)(dst + wr * 64 + wg * 8 + 8) = v1;
    *(uint4*)(dst2 + wr * 64 + wg * 8) = v0;
    *(uint4*)(dst2 + wr * 64 + wg * 8 + 8) = v1;
  }
}

// ---------------- carry chain: z_{16(c+1)} = (I + S15_c) z_{16c}; compact S15 reads
__global__ __launch_bounds__(64) void k_carry(const float* __restrict__ zin,
                                              const u16* __restrict__ S15,
                                              float* __restrict__ out) {
  int b = blockIdx.x, l = threadIdx.x;
  uint4 cf[8], nf[8];
  {
    const uint4* M0 = (const uint4*)(S15 + (size_t)(b * 32) * 4096 + l * 64);
#pragma unroll
    for (int g = 0; g < 8; ++g) cf[g] = M0[g];
  }
  float cz = zin[(size_t)b * 512 * 64 + l];
  for (int c = 0; c < 32; ++c) {
    out[((size_t)(b * 512 + c * 16)) * 64 + l] = cz;
    if (c < 31) {
      const uint4* Mn = (const uint4*)(S15 + (size_t)(b * 32 + c + 1) * 4096 + l * 64);
#pragma unroll
      for (int g = 0; g < 8; ++g) nf[g] = Mn[g];
    }
    float a0 = 0.f, a1 = 0.f, a2 = 0.f, a3 = 0.f;
#pragma unroll
    for (int g = 0; g < 8; ++g) {
      uint4 v = cf[g];
      int k = g * 8;
      a0 = fmaf(bflo(v.x), __shfl(cz, k + 0), a0);
      a1 = fmaf(bfhi(v.x), __shfl(cz, k + 1), a1);
      a2 = fmaf(bflo(v.y), __shfl(cz, k + 2), a2);
      a3 = fmaf(bfhi(v.y), __shfl(cz, k + 3), a3);
      a0 = fmaf(bflo(v.z), __shfl(cz, k + 4), a0);
      a1 = fmaf(bfhi(v.z), __shfl(cz, k + 5), a1);
      a2 = fmaf(bflo(v.w), __shfl(cz, k + 6), a2);
      a3 = fmaf(bfhi(v.w), __shfl(cz, k + 7), a3);
    }
    cz += (a0 + a1) + (a2 + a3);
    if (c < 31) {
#pragma unroll
      for (int g = 0; g < 8; ++g) cf[g] = nf[g];
    }
  }
}

// ---------------- apply: z_{16c+j+1} = (I + S_j) z_{16c}; row-major S, vectorized rows
__global__ __launch_bounds__(256) void k_apply(const u16* __restrict__ R,
                                               float* __restrict__ out) {
  __shared__ float carr[64];
  int t = threadIdx.x, w = t >> 6, l = t & 63;
  int b = blockIdx.x >> 5, c = blockIdx.x & 31;
  const u16* Rb = R + ((size_t)(b * 512 + c * 16)) * 4096;
  if (t < 64) carr[t] = out[((size_t)(b * 512 + c * 16)) * 64 + t];
  __syncthreads();
  float zl = carr[l];
  for (int j = w; j < 15; j += 4) {
    const uint4* M = (const uint4*)(Rb + (size_t)j * 4096 + l * 64);
    float a0 = 0.f, a1 = 0.f, a2 = 0.f, a3 = 0.f;
#pragma unroll
    for (int g = 0; g < 8; ++g) {
      uint4 v = M[g];
      const float* zb = &carr[g * 8];
      a0 = fmaf(bflo(v.x), zb[0], a0);
      a1 = fmaf(bfhi(v.x), zb[1], a1);
      a2 = fmaf(bflo(v.y), zb[2], a2);
      a3 = fmaf(bfhi(v.y), zb[3], a3);
      a0 = fmaf(bflo(v.z), zb[4], a0);
      a1 = fmaf(bfhi(v.z), zb[5], a1);
      a2 = fmaf(bflo(v.w), zb[6], a2);
      a3 = fmaf(bfhi(v.w), zb[7], a3);
    }
    out[((size_t)(b * 512 + c * 16 + j + 1)) * 64 + l] = zl + ((a0 + a1) + (a2 + a3));
  }
}

extern "C" void kernel_launch(void* const* d_in, const int* in_sizes, int n_in,
                              void* d_out, int out_size, void* d_ws, size_t ws_size,
                              hipStream_t stream) {
  const float* z_input  = (const float*)d_in[0];
  const float* dt       = (const float*)d_in[1];
  const float* ln1_w    = (const float*)d_in[2];
  const float* ln1_b    = (const float*)d_in[3];
  const float* Lam_re   = (const float*)d_in[4];
  const float* Lam_im   = (const float*)d_in[5];
  const float* B_re     = (const float*)d_in[6];
  const float* B_im     = (const float*)d_in[7];
  const float* C_re     = (const float*)d_in[8];
  const float* C_im     = (const float*)d_in[9];
  const float* Dp       = (const float*)d_in[10];
  const float* log_step = (const float*)d_in[11];
  const float* ln2_w    = (const float*)d_in[12];
  const float* ln2_b    = (const float*)d_in[13];
  const float* ff_enc   = (const float*)d_in[14];
  const float* ff_dec   = (const float*)d_in[15];
  const float* toA_w1   = (const float*)d_in[16];
  const float* toA_b1   = (const float*)d_in[17];
  const float* toA_w2   = (const float*)d_in[18];
  const float* toA_b2   = (const float*)d_in[19];
  const float* mask_A   = (const float*)d_in[20];

  char* ws = (char*)d_ws;
  float* wLbar = (float*)(ws + 0);
  float* wBbr  = (float*)(ws + 2048);
  float* wBbi  = (float*)(ws + 67584);
  float* wCtr  = (float*)(ws + 133120);
  float* wCti  = (float*)(ws + 198656);
  float* wfx   = (float*)(ws + 264192);
  float* wx    = (float*)(ws + 4458496);
  u32* wbu     = (u32*)(ws + 8652800);      // [16384][128] packed bf16 (re,im)
  u16* wS15    = (u16*)(ws + 17041408);     // [1024][4096] bf16 compact
  u16* wh1     = (u16*)(ws + 25430016);     // [16384][128] bf16
  u16* w2T     = (u16*)(ws + 29624320);     // [4096][128] bf16
  u16* wX      = (u16*)(ws + 30672896);     // [16384][4096] bf16 (X, then S in place)
  if (ws_size < 164890624ull) return;

  k_pre2<<<66, 256, 0, stream>>>(Lam_re, Lam_im, log_step, B_re, B_im, C_re, C_im,
                                 toA_w2, wLbar, wBbr, wBbi, wCtr, wCti, w2T);
  for (int l = 0; l < 2; ++l) {
    const float* xin = (l == 0) ? z_input : wx;
    k_ln_bu<<<512, 256, 0, stream>>>(xin, ln1_w, ln1_b, wBbr, wBbi, wfx, wbu, l);
    k_scan<<<256, 256, 0, stream>>>(wbu, wLbar, l);
    k_yff<<<512, 256, 0, stream>>>(wbu, wCtr, wCti, wfx, Dp, ln2_w, ln2_b, ff_enc, ff_dec,
                                   toA_w1, toA_b1, wx, wh1, l);
  }
  k_gemm_mfma<<<dim3(32, 128), 256, 0, stream>>>(w2T, wh1, toA_b2, mask_A, dt, wX);
  k_chunk<<<1024, 256, 0, stream>>>(wX, wS15);
  k_carry<<<32, 64, 0, stream>>>(z_input, wS15, (float*)d_out);
  k_apply<<<1024, 256, 0, stream>>>(wX, (float*)d_out);
}